// Round 4
// baseline (827.108 us; speedup 1.0000x reference)
//
#include <hip/hip_runtime.h>
#include <math.h>

// Problem constants: h [B,T,D] fp32, k scalar fp32.
#define BB 8
#define TT 2048
#define DD 512
#define LL 16            // chunk length along T (16 float4/lane -> registers)
#define CC (TT / LL)     // 128 chunks
#define D4 (DD / 4)      // 128 float4 lanes = block size
#define NBLK (BB * CC)   // 1024 blocks
#define SCAN_BLKS (BB * DD / 128)   // 32 blocks handle the column scan

__device__ __forceinline__ float get_s(const float* kp) {
    float k = *kp;
    return (k > 20.0f) ? k : log1pf(expf(k));   // softplus, stable
}

// Two-level grid barrier. sync layout per phase: 16 spread counters at
// sync + phase*64, release flag at sync + phase*64 + 32 (separate line).
// Only threadIdx.x==0 touches atomics (R3 lesson: no block-wide polling).
__device__ __forceinline__ void grid_barrier(int* __restrict__ sync, int phase) {
    __syncthreads();
    if (threadIdx.x == 0) {
        int* cnt = sync + phase * 64;
        int* rel = cnt + 32;
        __threadfence();   // release all prior global writes (agent scope)
        __hip_atomic_fetch_add(cnt + (blockIdx.x & 15), 1,
                               __ATOMIC_ACQ_REL, __HIP_MEMORY_SCOPE_AGENT);
        if (blockIdx.x == 0) {
            int s;
            do {
                s = 0;
                #pragma unroll
                for (int i = 0; i < 16; i++)
                    s += __hip_atomic_load(cnt + i, __ATOMIC_ACQUIRE,
                                           __HIP_MEMORY_SCOPE_AGENT);
                if (s < NBLK) __builtin_amdgcn_s_sleep(2);
            } while (s < NBLK);
            __hip_atomic_store(rel, 1, __ATOMIC_RELEASE,
                               __HIP_MEMORY_SCOPE_AGENT);
        } else {
            while (__hip_atomic_load(rel, __ATOMIC_ACQUIRE,
                                     __HIP_MEMORY_SCOPE_AGENT) == 0)
                __builtin_amdgcn_s_sleep(2);
        }
        __threadfence();   // acquire side: no stale L1/L2 after this
    }
    __syncthreads();
}

__global__ __launch_bounds__(D4) void k_one(
    const float* __restrict__ h, const float* __restrict__ kp,
    float* __restrict__ csum, float* __restrict__ cend,
    float* __restrict__ coff, float* __restrict__ ccar,
    int*   __restrict__ sync,
    float* __restrict__ out)
{
    const int blk = blockIdx.x;
    const int b = blk / CC, c = blk % CC;
    const int tid = threadIdx.x;
    const int wave = tid >> 6, lane = tid & 63;
    const float s  = get_s(kp);
    const float a  = expf(-s);
    const float aL = expf(-s * (float)LL);     // a^L

    const int t0 = c * LL;
    const float4* hp = reinterpret_cast<const float4*>(h)
                     + (size_t)(b * TT + t0) * D4 + tid;

    // ---- phase 1: chunk -> registers, aggregates S (sum) and E (decayed end)
    float px = 0.f, py = 0.f, pz = 0.f, pw = 0.f;   // h[t0-1]
    if (t0 > 0) {
        float4 pv = hp[-(size_t)D4];
        px = pv.x; py = pv.y; pz = pv.z; pw = pv.w;
    }

    float4 x[LL];
    #pragma unroll
    for (int i = 0; i < LL; i++) x[i] = hp[(size_t)i * D4];

    float sx = 0.f, sy = 0.f, sz = 0.f, sw = 0.f;
    float ex = 0.f, ey = 0.f, ez = 0.f, ew = 0.f;
    #pragma unroll
    for (int i = 0; i < LL; i++) {
        sx += x[i].x; sy += x[i].y; sz += x[i].z; sw += x[i].w;
        ex = fmaf(a, ex, x[i].x);
        ey = fmaf(a, ey, x[i].y);
        ez = fmaf(a, ez, x[i].z);
        ew = fmaf(a, ew, x[i].w);
    }
    const size_t ci = (size_t)blk * D4 + tid;
    reinterpret_cast<float4*>(csum)[ci] = make_float4(sx, sy, sz, sw);
    reinterpret_cast<float4*>(cend)[ci] = make_float4(ex, ey, ez, ew);

    grid_barrier(sync, 0);

    // ---- phase 2: 32 blocks scan the (b,d) columns over chunks (exclusive)
    if (blk < SCAN_BLKS) {
        const int g = blk * D4 + tid;      // 0 .. B*D-1
        const int sb = g >> 9;             // /512
        const int sd = g & (DD - 1);       // %512
        const size_t base = (size_t)sb * CC * DD + sd;
        float co = 0.f, cc = 0.f;
        #pragma unroll 8
        for (int cp = 0; cp < CC; cp++) {
            const size_t idx = base + (size_t)cp * DD;
            float sv = csum[idx];
            float ev = cend[idx];
            coff[idx] = co;
            ccar[idx] = cc;
            co += sv;
            cc = fmaf(aL, cc, ev);
        }
    }

    grid_barrier(sync, 1);

    // ---- phase 3: O(1) carries, mags, ctx recurrence, output
    float4 co4 = reinterpret_cast<const float4*>(coff)[ci];
    float4 cc4 = reinterpret_cast<const float4*>(ccar)[ci];

    __shared__ float m2s[2][LL];
    __shared__ float mags[LL];

    float cox = co4.x, coy = co4.y, coz = co4.z, cow = co4.w;
    #pragma unroll
    for (int i = 0; i < LL; i++) {
        cox += x[i].x; coy += x[i].y; coz += x[i].z; cow += x[i].w;
        float dx = cox - px, dy = coy - py, dz = coz - pz, dw = cow - pw;
        float r = dx * dx + dy * dy + dz * dz + dw * dw;
        px = x[i].x; py = x[i].y; pz = x[i].z; pw = x[i].w;
        #pragma unroll
        for (int m = 32; m > 0; m >>= 1) r += __shfl_xor(r, m, 64);
        if (lane == 0) m2s[wave][i] = r;
    }
    __syncthreads();
    if (tid < LL) mags[tid] = sqrtf(m2s[0][tid] + m2s[1][tid]);
    __syncthreads();

    float4* op = reinterpret_cast<float4*>(out)
               + (size_t)(b * TT + t0) * D4 + tid;
    float ccx = cc4.x, ccy = cc4.y, ccz = cc4.z, ccw = cc4.w;
    #pragma unroll
    for (int i = 0; i < LL; i++) {
        ccx = fmaf(a, ccx, x[i].x);
        ccy = fmaf(a, ccy, x[i].y);
        ccz = fmaf(a, ccz, x[i].z);
        ccw = fmaf(a, ccw, x[i].w);
        float m = mags[i];
        op[(size_t)i * D4] = make_float4(fabsf(m * ccx), fabsf(m * ccy),
                                         fabsf(m * ccz), fabsf(m * ccw));
    }
}

extern "C" void kernel_launch(void* const* d_in, const int* in_sizes, int n_in,
                              void* d_out, int out_size, void* d_ws, size_t ws_size,
                              hipStream_t stream) {
    const float* h  = (const float*)d_in[0];
    const float* kp = (const float*)d_in[1];
    float* out = (float*)d_out;

    const size_t NS = (size_t)BB * CC * DD;   // 512K floats = 2 MB each
    float* csum = (float*)d_ws;
    float* cend = csum + NS;
    float* coff = cend + NS;
    float* ccar = coff + NS;
    int*   sync = (int*)(ccar + NS);          // 128 ints = 512 B

    hipMemsetAsync(sync, 0, 128 * sizeof(int), stream);

    void* args[] = { (void*)&h, (void*)&kp, (void*)&csum, (void*)&cend,
                     (void*)&coff, (void*)&ccar, (void*)&sync, (void*)&out };
    hipLaunchCooperativeKernel((const void*)k_one, dim3(NBLK), dim3(D4),
                               args, 0, stream);
}

// Round 5
// 110.090 us; speedup vs baseline: 7.5130x; 7.5130x over previous
//
#include <hip/hip_runtime.h>
#include <math.h>

// Problem constants: h [B,T,D] fp32, k scalar fp32.
#define BB 8
#define TT 2048
#define DD 512
#define LL 8             // chunk length along T (8 float4/lane -> registers, guaranteed)
#define CC (TT / LL)     // 256 chunks
#define D4 (DD / 4)      // 128 float4 lanes = block size
#define NBLK (BB * CC)   // 2048 blocks

__device__ __forceinline__ float get_s(const float* kp) {
    float k = *kp;
    return (k > 20.0f) ? k : log1pf(expf(k));   // softplus, stable
}

// ---------------------------------------------------------------------------
// Kernel 1: per (b,c): chunk sum + locally-decayed chunk end (streaming).
//   csum[b][c][d] = sum_{i<L} h[b, c*L+i, d]
//   cend[b][c][d] = sum_{i<L} a^(L-1-i) h[b, c*L+i, d]
// ---------------------------------------------------------------------------
__global__ __launch_bounds__(D4) void k1_chunk(
    const float* __restrict__ h, const float* __restrict__ kp,
    float* __restrict__ csum, float* __restrict__ cend)
{
    const int blk = blockIdx.x;
    const int b = blk / CC, c = blk % CC;
    const int tid = threadIdx.x;
    const float a = expf(-get_s(kp));

    const float4* hp = reinterpret_cast<const float4*>(h)
                     + (size_t)(b * TT + c * LL) * D4 + tid;

    float4 x[LL];
    #pragma unroll
    for (int i = 0; i < LL; i++) x[i] = hp[(size_t)i * D4];

    float sx = 0.f, sy = 0.f, sz = 0.f, sw = 0.f;
    float ex = 0.f, ey = 0.f, ez = 0.f, ew = 0.f;
    #pragma unroll
    for (int i = 0; i < LL; i++) {
        sx += x[i].x; sy += x[i].y; sz += x[i].z; sw += x[i].w;
        ex = fmaf(a, ex, x[i].x);
        ey = fmaf(a, ey, x[i].y);
        ez = fmaf(a, ez, x[i].z);
        ew = fmaf(a, ew, x[i].w);
    }
    const size_t w = (size_t)blk * D4 + tid;
    reinterpret_cast<float4*>(csum)[w] = make_float4(sx, sy, sz, sw);
    reinterpret_cast<float4*>(cend)[w] = make_float4(ex, ey, ez, ew);
}

// ---------------------------------------------------------------------------
// Kernel 2: in-place exclusive scan over chunks, per (b,d) float column.
// After this kernel:  csum[b][c][d] = sum_{cp<c} (old csum)[b][cp][d]
//                     cend[b][c][d] = sum_{cp<c} aL^(c-1-cp) (old cend)[b][cp][d]
// grid = 32 blocks x 128 threads; lanes cover consecutive d (coalesced).
// ---------------------------------------------------------------------------
__global__ __launch_bounds__(128) void k2_scan(
    float* __restrict__ csum, float* __restrict__ cend,
    const float* __restrict__ kp)
{
    const int g = blockIdx.x * 128 + threadIdx.x;   // 0 .. B*D-1
    const int b = g >> 9;          // /512
    const int d = g & (DD - 1);    // %512
    const float s  = get_s(kp);
    const float aL = expf(-s * (float)LL);

    const size_t base = (size_t)b * CC * DD + d;
    float co = 0.f, cc = 0.f;
    #pragma unroll 16
    for (int c = 0; c < CC; c++) {
        const size_t idx = base + (size_t)c * DD;
        float sv = csum[idx];
        float ev = cend[idx];
        csum[idx] = co;            // exclusive prefix, in place
        cend[idx] = cc;
        co += sv;
        cc = fmaf(aL, cc, ev);
    }
}

// ---------------------------------------------------------------------------
// Kernel 3: per (b,c): O(1) carry load, chunk in registers (x[8] = 32 VGPR).
// Phase A: cumsum chain -> per-thread r[i]; batched independent butterfly
// shuffles; one barrier; mags rebuilt in registers by every thread.
// Phase B: ctx recurrence from registers, write |mag*ctx|.
// ---------------------------------------------------------------------------
__global__ __launch_bounds__(D4) void k3_out(
    const float* __restrict__ h, const float* __restrict__ kp,
    const float* __restrict__ coff, const float* __restrict__ ccar,
    float* __restrict__ out)
{
    const int blk = blockIdx.x;
    const int b = blk / CC, c = blk % CC;
    const int tid = threadIdx.x;
    const int wave = tid >> 6, lane = tid & 63;
    const float a = expf(-get_s(kp));

    const int t0 = c * LL;
    const float4* hp = reinterpret_cast<const float4*>(h)
                     + (size_t)(b * TT + t0) * D4 + tid;

    // carries (exclusive prefixes from k2) — issue loads early
    const size_t ci = (size_t)blk * D4 + tid;
    float4 co4 = reinterpret_cast<const float4*>(coff)[ci];
    float4 cc4 = reinterpret_cast<const float4*>(ccar)[ci];

    float px = 0.f, py = 0.f, pz = 0.f, pw = 0.f;   // h[t0-1]
    if (t0 > 0) {
        float4 pv = hp[-(size_t)D4];
        px = pv.x; py = pv.y; pz = pv.z; pw = pv.w;
    }

    float4 x[LL];
    #pragma unroll
    for (int i = 0; i < LL; i++) x[i] = hp[(size_t)i * D4];

    // ---- phase A: cumsum chain, per-thread delta^2 partials
    float r[LL];
    float cox = co4.x, coy = co4.y, coz = co4.z, cow = co4.w;
    #pragma unroll
    for (int i = 0; i < LL; i++) {
        cox += x[i].x; coy += x[i].y; coz += x[i].z; cow += x[i].w;
        float dx = cox - px, dy = coy - py, dz = coz - pz, dw = cow - pw;
        r[i] = dx * dx + dy * dy + dz * dz + dw * dw;
        px = x[i].x; py = x[i].y; pz = x[i].z; pw = x[i].w;
    }

    // batched butterfly: 6 rounds x 8 independent values (ILP-pipelined)
    #pragma unroll
    for (int m = 1; m < 64; m <<= 1) {
        #pragma unroll
        for (int i = 0; i < LL; i++) r[i] += __shfl_xor(r[i], m, 64);
    }

    __shared__ float part[2][LL];
    if (lane == 0) {
        #pragma unroll
        for (int i = 0; i < LL; i++) part[wave][i] = r[i];
    }
    __syncthreads();

    float mag[LL];
    #pragma unroll
    for (int i = 0; i < LL; i++) mag[i] = sqrtf(part[0][i] + part[1][i]);

    // ---- phase B: ctx recurrence from registers, write |mag*ctx|
    float4* op = reinterpret_cast<float4*>(out)
               + (size_t)(b * TT + t0) * D4 + tid;
    float ccx = cc4.x, ccy = cc4.y, ccz = cc4.z, ccw = cc4.w;
    #pragma unroll
    for (int i = 0; i < LL; i++) {
        ccx = fmaf(a, ccx, x[i].x);
        ccy = fmaf(a, ccy, x[i].y);
        ccz = fmaf(a, ccz, x[i].z);
        ccw = fmaf(a, ccw, x[i].w);
        float m = mag[i];
        op[(size_t)i * D4] = make_float4(fabsf(m * ccx), fabsf(m * ccy),
                                         fabsf(m * ccz), fabsf(m * ccw));
    }
}

extern "C" void kernel_launch(void* const* d_in, const int* in_sizes, int n_in,
                              void* d_out, int out_size, void* d_ws, size_t ws_size,
                              hipStream_t stream) {
    const float* h  = (const float*)d_in[0];
    const float* kp = (const float*)d_in[1];
    float* out = (float*)d_out;

    const size_t NS = (size_t)BB * CC * DD;   // 1M floats = 4 MB each
    float* csum = (float*)d_ws;
    float* cend = csum + NS;

    k1_chunk<<<dim3(NBLK), dim3(D4), 0, stream>>>(h, kp, csum, cend);
    k2_scan <<<dim3(BB * DD / 128), dim3(128), 0, stream>>>(csum, cend, kp);
    k3_out  <<<dim3(NBLK), dim3(D4), 0, stream>>>(h, kp, csum, cend, out);
}

// Round 6
// 99.701 us; speedup vs baseline: 8.2959x; 1.1042x over previous
//
#include <hip/hip_runtime.h>
#include <math.h>

// Problem constants: h [B,T,D] fp32, k scalar fp32.
#define BB 8
#define TT 2048
#define DD 512
#define LL 16             // chunk length along T
#define CC (TT / LL)      // 128 chunks
#define D4 (DD / 4)       // 128 float4 lanes = block size
#define NBLK (BB * CC)    // 1024 blocks
#define SEGS 4            // segments per column in k2
#define SEGLEN (CC / SEGS)// 32 chunks per segment
#define NCOL (BB * DD)    // 4096 scan columns

__device__ __forceinline__ float get_s(const float* kp) {
    float k = *kp;
    return (k > 20.0f) ? k : log1pf(expf(k));   // softplus, stable
}

// ---------------------------------------------------------------------------
// Kernel 1: per (b,c): streaming chunk sum + locally-decayed chunk end.
//   csum[b][c][d] = sum_{i<L} h[b, c*L+i, d]
//   cend[b][c][d] = sum_{i<L} a^(L-1-i) h[b, c*L+i, d]
// Low VGPR (no x[] retention) -> high occupancy, pure BW streaming.
// ---------------------------------------------------------------------------
__global__ __launch_bounds__(D4) void k1_chunk(
    const float* __restrict__ h, const float* __restrict__ kp,
    float* __restrict__ csum, float* __restrict__ cend)
{
    const int blk = blockIdx.x;
    const int b = blk / CC, c = blk % CC;
    const int tid = threadIdx.x;
    const float a = expf(-get_s(kp));

    const float4* hp = reinterpret_cast<const float4*>(h)
                     + (size_t)(b * TT + c * LL) * D4 + tid;

    float sx = 0.f, sy = 0.f, sz = 0.f, sw = 0.f;
    float ex = 0.f, ey = 0.f, ez = 0.f, ew = 0.f;
    #pragma unroll
    for (int i = 0; i < LL; i++) {
        float4 x = hp[(size_t)i * D4];
        sx += x.x; sy += x.y; sz += x.z; sw += x.w;
        ex = fmaf(a, ex, x.x);
        ey = fmaf(a, ey, x.y);
        ez = fmaf(a, ez, x.z);
        ew = fmaf(a, ew, x.w);
    }
    const size_t w = (size_t)blk * D4 + tid;
    reinterpret_cast<float4*>(csum)[w] = make_float4(sx, sy, sz, sw);
    reinterpret_cast<float4*>(cend)[w] = make_float4(ex, ey, ez, ew);
}

// ---------------------------------------------------------------------------
// Kernel 2: hierarchical in-place exclusive scan over chunks per (b,d) column.
// Column split into SEGS segments handled by SEGS threads of one block;
// cross-segment carry via LDS. Serial length 32+32 instead of 128.
// After: csum[b][c][d] = sum_{cp<c} S[cp],  cend[b][c][d] = decayed carry.
// grid = NCOL*SEGS/256 = 64 blocks x 256 threads.
// wave = one segment of 64 consecutive columns -> coalesced, LDS conflict-free.
// ---------------------------------------------------------------------------
__global__ __launch_bounds__(256) void k2_scan(
    float* __restrict__ csum, float* __restrict__ cend,
    const float* __restrict__ kp)
{
    const int tid = threadIdx.x;
    const int cl  = tid & 63;          // column within block
    const int seg = tid >> 6;          // 0..3
    const int col = blockIdx.x * 64 + cl;   // 0 .. NCOL-1
    const int b = col >> 9;            // /512
    const int d = col & (DD - 1);      // %512
    const float s    = get_s(kp);
    const float aL   = expf(-s * (float)LL);            // a^LL
    const float aL32 = expf(-s * (float)(LL * SEGLEN)); // a^(LL*32)

    const size_t base = (size_t)b * CC * DD + d;
    const int c0 = seg * SEGLEN;

    // phase 1: segment aggregates (read-only)
    float Sa = 0.f, Ea = 0.f;
    #pragma unroll 8
    for (int c = c0; c < c0 + SEGLEN; c++) {
        const size_t idx = base + (size_t)c * DD;
        Sa += csum[idx];
        Ea = fmaf(aL, Ea, cend[idx]);
    }

    __shared__ float sS[SEGS][64];
    __shared__ float sE[SEGS][64];
    sS[seg][cl] = Sa;
    sE[seg][cl] = Ea;
    __syncthreads();

    // phase 2: exclusive cross-segment carries (trip count uniform per wave)
    float off = 0.f, car = 0.f;
    for (int sp = 0; sp < seg; sp++) {
        off += sS[sp][cl];
        car = fmaf(aL32, car, sE[sp][cl]);
    }

    // phase 3: re-scan segment, write exclusive prefixes in place
    float co = off, cc = car;
    #pragma unroll 8
    for (int c = c0; c < c0 + SEGLEN; c++) {
        const size_t idx = base + (size_t)c * DD;
        float sv = csum[idx];
        float ev = cend[idx];
        csum[idx] = co;
        cend[idx] = cc;
        co += sv;
        cc = fmaf(aL, cc, ev);
    }
}

// ---------------------------------------------------------------------------
// Kernel 3: per (b,c): O(1) carry load; TWO passes over the chunk's h
// (second pass is cache-warm) instead of x[16] retention the compiler
// refuses to honor (R4: VGPR_Count=60 < 64 needed -> hidden spills/reloads).
// Pass A: cumsum chain -> r[16]; batched butterfly shuffles; mags.
// Pass B: ctx recurrence, write |mag*ctx|.
// ---------------------------------------------------------------------------
__global__ __launch_bounds__(D4) void k3_out(
    const float* __restrict__ h, const float* __restrict__ kp,
    const float* __restrict__ coff, const float* __restrict__ ccar,
    float* __restrict__ out)
{
    const int blk = blockIdx.x;
    const int b = blk / CC, c = blk % CC;
    const int tid = threadIdx.x;
    const int wave = tid >> 6, lane = tid & 63;
    const float a = expf(-get_s(kp));

    const int t0 = c * LL;
    const float4* hp = reinterpret_cast<const float4*>(h)
                     + (size_t)(b * TT + t0) * D4 + tid;

    // carries (exclusive prefixes from k2)
    const size_t ci = (size_t)blk * D4 + tid;
    float4 co4 = reinterpret_cast<const float4*>(coff)[ci];
    float4 cc4 = reinterpret_cast<const float4*>(ccar)[ci];

    float px = 0.f, py = 0.f, pz = 0.f, pw = 0.f;   // h[t0-1]
    if (t0 > 0) {
        float4 pv = hp[-(size_t)D4];
        px = pv.x; py = pv.y; pz = pv.z; pw = pv.w;
    }

    // ---- pass A: cumsum chain, per-thread delta^2 partials
    float r[LL];
    float cox = co4.x, coy = co4.y, coz = co4.z, cow = co4.w;
    #pragma unroll
    for (int i = 0; i < LL; i++) {
        float4 x = hp[(size_t)i * D4];
        cox += x.x; coy += x.y; coz += x.z; cow += x.w;
        float dx = cox - px, dy = coy - py, dz = coz - pz, dw = cow - pw;
        r[i] = dx * dx + dy * dy + dz * dz + dw * dw;
        px = x.x; py = x.y; pz = x.z; pw = x.w;
    }

    // batched butterfly: 6 rounds x 16 independent values (ILP-pipelined)
    #pragma unroll
    for (int m = 1; m < 64; m <<= 1) {
        #pragma unroll
        for (int i = 0; i < LL; i++) r[i] += __shfl_xor(r[i], m, 64);
    }

    __shared__ float part[2][LL];
    if (lane == 0) {
        #pragma unroll
        for (int i = 0; i < LL; i++) part[wave][i] = r[i];
    }
    __syncthreads();

    float mag[LL];
    #pragma unroll
    for (int i = 0; i < LL; i++) mag[i] = sqrtf(part[0][i] + part[1][i]);

    // ---- pass B: ctx recurrence, h re-read is L1/L2/LLC-warm
    float4* op = reinterpret_cast<float4*>(out)
               + (size_t)(b * TT + t0) * D4 + tid;
    float ccx = cc4.x, ccy = cc4.y, ccz = cc4.z, ccw = cc4.w;
    #pragma unroll
    for (int i = 0; i < LL; i++) {
        float4 x = hp[(size_t)i * D4];
        ccx = fmaf(a, ccx, x.x);
        ccy = fmaf(a, ccy, x.y);
        ccz = fmaf(a, ccz, x.z);
        ccw = fmaf(a, ccw, x.w);
        float m = mag[i];
        op[(size_t)i * D4] = make_float4(fabsf(m * ccx), fabsf(m * ccy),
                                         fabsf(m * ccz), fabsf(m * ccw));
    }
}

extern "C" void kernel_launch(void* const* d_in, const int* in_sizes, int n_in,
                              void* d_out, int out_size, void* d_ws, size_t ws_size,
                              hipStream_t stream) {
    const float* h  = (const float*)d_in[0];
    const float* kp = (const float*)d_in[1];
    float* out = (float*)d_out;

    const size_t NS = (size_t)BB * CC * DD;   // 512K floats = 2 MB each
    float* csum = (float*)d_ws;
    float* cend = csum + NS;

    k1_chunk<<<dim3(NBLK), dim3(D4), 0, stream>>>(h, kp, csum, cend);
    k2_scan <<<dim3(NCOL * SEGS / 256), dim3(256), 0, stream>>>(csum, cend, kp);
    k3_out  <<<dim3(NBLK), dim3(D4), 0, stream>>>(h, kp, csum, cend, out);
}

// Round 8
// 96.630 us; speedup vs baseline: 8.5595x; 1.0318x over previous
//
#include <hip/hip_runtime.h>
#include <math.h>

// Problem constants: h [B,T,D] fp32, k scalar fp32.
#define BB 8
#define TT 2048
#define DD 512
#define LL 16             // chunk length (t-steps)
#define CC (TT / LL)      // 128 chunks per b
#define D4 (DD / 4)       // 128 float4 lanes = block size
#define SCT 64            // superchunk length (t-steps)
#define NSC (TT / SCT)    // 32 superchunks per b
#define CPS (SCT / LL)    // 4 chunks per superchunk

typedef float floatx4 __attribute__((ext_vector_type(4)));

__device__ __forceinline__ float get_s(const float* kp) {
    float k = *kp;
    return (k > 20.0f) ? k : log1pf(expf(k));   // softplus, stable
}

// ---------------------------------------------------------------------------
// Kernel A: block = (b, superchunk). Streams 64 t-steps of h once; emits
// chunk-level stats (sum S, decayed-end E per 16 t) and superchunk-level
// stats (per 64 t). Grid = 8*32 = 256 blocks x 128 threads.
// ---------------------------------------------------------------------------
__global__ __launch_bounds__(D4) void kA_stats(
    const float* __restrict__ h, const float* __restrict__ kp,
    float* __restrict__ csum, float* __restrict__ cend,
    float* __restrict__ ssum, float* __restrict__ send)
{
    const int blk = blockIdx.x;
    const int b = blk / NSC, sc = blk % NSC;
    const int tid = threadIdx.x;
    const float s   = get_s(kp);
    const float a   = expf(-s);
    const float a16 = expf(-s * (float)LL);

    const float4* hp = reinterpret_cast<const float4*>(h)
                     + (size_t)(b * TT + sc * SCT) * D4 + tid;

    float Sx = 0.f, Sy = 0.f, Sz = 0.f, Sw = 0.f;   // superchunk sum
    float Ex = 0.f, Ey = 0.f, Ez = 0.f, Ew = 0.f;   // superchunk decayed end

    #pragma unroll
    for (int j = 0; j < CPS; j++) {
        float sx = 0.f, sy = 0.f, sz = 0.f, sw = 0.f;
        float ex = 0.f, ey = 0.f, ez = 0.f, ew = 0.f;
        #pragma unroll
        for (int i = 0; i < LL; i++) {
            float4 x = hp[(size_t)(j * LL + i) * D4];
            sx += x.x; sy += x.y; sz += x.z; sw += x.w;
            ex = fmaf(a, ex, x.x);
            ey = fmaf(a, ey, x.y);
            ez = fmaf(a, ez, x.z);
            ew = fmaf(a, ew, x.w);
        }
        const size_t wi = (size_t)(b * CC + sc * CPS + j) * D4 + tid;
        reinterpret_cast<float4*>(csum)[wi] = make_float4(sx, sy, sz, sw);
        reinterpret_cast<float4*>(cend)[wi] = make_float4(ex, ey, ez, ew);
        Sx += sx; Sy += sy; Sz += sz; Sw += sw;
        Ex = fmaf(a16, Ex, ex);
        Ey = fmaf(a16, Ey, ey);
        Ez = fmaf(a16, Ez, ez);
        Ew = fmaf(a16, Ew, ew);
    }
    const size_t wi = (size_t)(b * NSC + sc) * D4 + tid;
    reinterpret_cast<float4*>(ssum)[wi] = make_float4(Sx, Sy, Sz, Sw);
    reinterpret_cast<float4*>(send)[wi] = make_float4(Ex, Ey, Ez, Ew);
}

// ---------------------------------------------------------------------------
// Kernel B: block = (b, chunk). Two-level redundant lookback (<=31 superchunk
// + <=3 chunk stats, L2/LLC hits, block-uniform trip counts) -> exact carries.
// Pass A: cumsum chain + LDS stash of the chunk + batched butterfly mags.
// Pass B: ctx recurrence from LDS, non-temporal |mag*ctx| store.
// Grid = 8*128 = 1024 blocks x 128 threads; 32 KB LDS -> 4 blocks/CU.
// ---------------------------------------------------------------------------
__global__ __launch_bounds__(D4) void kB_out(
    const float* __restrict__ h, const float* __restrict__ kp,
    const float* __restrict__ csum, const float* __restrict__ cend,
    const float* __restrict__ ssum, const float* __restrict__ send,
    float* __restrict__ out)
{
    const int blk = blockIdx.x;
    const int b = blk / CC, c = blk % CC;
    const int sc = c >> 2, j = c & (CPS - 1);
    const int tid = threadIdx.x;
    const int wave = tid >> 6, lane = tid & 63;
    const float s   = get_s(kp);
    const float a   = expf(-s);
    const float a16 = expf(-s * (float)LL);
    const float a64 = expf(-s * (float)SCT);

    // ---- lookback level 1: superchunks before sc
    float cox = 0.f, coy = 0.f, coz = 0.f, cow = 0.f;   // cumsum offset
    float ccx = 0.f, ccy = 0.f, ccz = 0.f, ccw = 0.f;   // ctx entering state
    {
        const float4* ss4 = reinterpret_cast<const float4*>(ssum)
                          + (size_t)(b * NSC) * D4 + tid;
        const float4* se4 = reinterpret_cast<const float4*>(send)
                          + (size_t)(b * NSC) * D4 + tid;
        float w = 1.f;
        for (int p = sc - 1; p >= 0; --p) {
            float4 sv = ss4[(size_t)p * D4];
            float4 ev = se4[(size_t)p * D4];
            cox += sv.x; coy += sv.y; coz += sv.z; cow += sv.w;
            ccx = fmaf(w, ev.x, ccx);
            ccy = fmaf(w, ev.y, ccy);
            ccz = fmaf(w, ev.z, ccz);
            ccw = fmaf(w, ev.w, ccw);
            w *= a64;
        }
    }
    // ---- lookback level 2: chunks before j inside superchunk sc
    {
        const float4* cs4 = reinterpret_cast<const float4*>(csum)
                          + (size_t)(b * CC + sc * CPS) * D4 + tid;
        const float4* ce4 = reinterpret_cast<const float4*>(cend)
                          + (size_t)(b * CC + sc * CPS) * D4 + tid;
        float wj = 1.f;
        float cIx = 0.f, cIy = 0.f, cIz = 0.f, cIw = 0.f;
        for (int p = j - 1; p >= 0; --p) {
            float4 sv = cs4[(size_t)p * D4];
            float4 ev = ce4[(size_t)p * D4];
            cox += sv.x; coy += sv.y; coz += sv.z; cow += sv.w;
            cIx = fmaf(wj, ev.x, cIx);
            cIy = fmaf(wj, ev.y, cIy);
            cIz = fmaf(wj, ev.z, cIz);
            cIw = fmaf(wj, ev.w, cIw);
            wj *= a16;
        }
        // ctx entering chunk = (superchunk carry) * a16^j + intra part
        ccx = fmaf(wj, ccx, cIx);
        ccy = fmaf(wj, ccy, cIy);
        ccz = fmaf(wj, ccz, cIz);
        ccw = fmaf(wj, ccw, cIw);
    }

    const int t0 = c * LL;
    const float4* hp = reinterpret_cast<const float4*>(h)
                     + (size_t)(b * TT + t0) * D4 + tid;

    float px = 0.f, py = 0.f, pz = 0.f, pw = 0.f;   // h[t0-1]
    if (t0 > 0) {
        float4 pv = *(hp - (ptrdiff_t)D4);
        px = pv.x; py = pv.y; pz = pv.z; pw = pv.w;
    }

    __shared__ float4 stash[LL][D4];   // 32 KB chunk stash
    __shared__ float part[2][LL];

    // ---- pass A: cumsum chain, per-thread delta^2 partials, LDS stash
    float r[LL];
    #pragma unroll
    for (int i = 0; i < LL; i++) {
        float4 x = hp[(size_t)i * D4];
        stash[i][tid] = x;
        cox += x.x; coy += x.y; coz += x.z; cow += x.w;
        float dx = cox - px, dy = coy - py, dz = coz - pz, dw = cow - pw;
        r[i] = dx * dx + dy * dy + dz * dz + dw * dw;
        px = x.x; py = x.y; pz = x.z; pw = x.w;
    }

    // batched butterfly: 6 rounds x 16 independent values
    #pragma unroll
    for (int m = 1; m < 64; m <<= 1) {
        #pragma unroll
        for (int i = 0; i < LL; i++) r[i] += __shfl_xor(r[i], m, 64);
    }
    if (lane == 0) {
        #pragma unroll
        for (int i = 0; i < LL; i++) part[wave][i] = r[i];
    }
    __syncthreads();   // also covers the LDS stash

    float mag[LL];
    #pragma unroll
    for (int i = 0; i < LL; i++) mag[i] = sqrtf(part[0][i] + part[1][i]);

    // ---- pass B: ctx recurrence from LDS, non-temporal output store
    floatx4* op = reinterpret_cast<floatx4*>(out)
                + (size_t)(b * TT + t0) * D4 + tid;
    #pragma unroll
    for (int i = 0; i < LL; i++) {
        float4 x = stash[i][tid];
        ccx = fmaf(a, ccx, x.x);
        ccy = fmaf(a, ccy, x.y);
        ccz = fmaf(a, ccz, x.z);
        ccw = fmaf(a, ccw, x.w);
        float m = mag[i];
        floatx4 o;
        o.x = fabsf(m * ccx); o.y = fabsf(m * ccy);
        o.z = fabsf(m * ccz); o.w = fabsf(m * ccw);
        __builtin_nontemporal_store(o, op + (size_t)i * D4);
    }
}

extern "C" void kernel_launch(void* const* d_in, const int* in_sizes, int n_in,
                              void* d_out, int out_size, void* d_ws, size_t ws_size,
                              hipStream_t stream) {
    const float* h  = (const float*)d_in[0];
    const float* kp = (const float*)d_in[1];
    float* out = (float*)d_out;

    const size_t NC = (size_t)BB * CC * DD;    // 512K floats = 2 MB each
    const size_t NSb = (size_t)BB * NSC * DD;  // 128K floats = 512 KB each
    float* csum = (float*)d_ws;
    float* cend = csum + NC;
    float* ssum = cend + NC;
    float* send = ssum + NSb;

    kA_stats<<<dim3(BB * NSC), dim3(D4), 0, stream>>>(h, kp, csum, cend, ssum, send);
    kB_out  <<<dim3(BB * CC),  dim3(D4), 0, stream>>>(h, kp, csum, cend, ssum, send, out);
}